// Round 1
// baseline (1988.382 us; speedup 1.0000x reference)
//
#include <hip/hip_runtime.h>

typedef __bf16 bf16x8 __attribute__((ext_vector_type(8)));
typedef float f32x4 __attribute__((ext_vector_type(4)));
typedef unsigned short u16;
typedef unsigned int u32;

#define D_DIM 4096
#define B_ROWS 16384
#define K_CLS 14
#define M_TOT 32768

// ---------- helpers ----------
__device__ __forceinline__ u32 f2bf(float f) {
    u32 u = __float_as_uint(f);
    return (u + 0x7FFFu + ((u >> 16) & 1u)) >> 16;   // RNE
}
__device__ __forceinline__ float bfl(u32 u) { return __uint_as_float(u << 16); }
__device__ __forceinline__ float bfh(u32 u) { return __uint_as_float(u & 0xFFFF0000u); }

typedef __attribute__((address_space(3))) void lds_void;
typedef __attribute__((address_space(1))) void glb_void;

// async global->LDS, 16B per lane; LDS dest = wave-uniform base + lane*16
__device__ __forceinline__ void g2lds16(const void* g, void* l) {
    __builtin_amdgcn_global_load_lds(
        reinterpret_cast<glb_void*>(reinterpret_cast<uintptr_t>(g)),
        reinterpret_cast<lds_void*>(reinterpret_cast<uintptr_t>(l)),
        16, 0, 0);
}

// ---------- cast f32 -> bf16 (4 elems/thread) ----------
__global__ void cast_bf16(const float* __restrict__ src, u16* __restrict__ dst, int n4) {
    int i = blockIdx.x * blockDim.x + threadIdx.x;
    int stride = gridDim.x * blockDim.x;
    for (; i < n4; i += stride) {
        float4 a = ((const float4*)src)[i];
        uint2 o;
        o.x = f2bf(a.x) | (f2bf(a.y) << 16);
        o.y = f2bf(a.z) | (f2bf(a.w) << 16);
        ((uint2*)dst)[i] = o;
    }
}

// ---------- prototype normalize + passthrough copy ----------
// pTbf layout: [D][16] bf16 (k-major inner, pad 14->16), for simproj reads
__global__ void proto_norm(const float* __restrict__ P, u16* __restrict__ pTbf,
                           float* __restrict__ outProto) {
    const int k = blockIdx.x;
    const int tid = threadIdx.x;
    float ss = 0.f;
    for (int d = tid; d < D_DIM; d += 256) {
        float v = P[k * D_DIM + d];
        ss += v * v;
    }
    for (int off = 32; off; off >>= 1) ss += __shfl_down(ss, off);
    __shared__ float red[4];
    if ((tid & 63) == 0) red[tid >> 6] = ss;
    __syncthreads();
    float tot = red[0] + red[1] + red[2] + red[3];
    float inv = 1.0f / fmaxf(sqrtf(tot), 1e-12f);
    for (int d = tid; d < D_DIM; d += 256) {
        float v = P[k * D_DIM + d];
        outProto[k * D_DIM + d] = v;                       // exact passthrough
        pTbf[(size_t)d * 16 + k] = (u16)f2bf(v * inv);
    }
}

// ---------- batch co-occurrence: one block per (i,j) pair ----------
__global__ void cooccur_bc(const int* __restrict__ L, float* __restrict__ bc) {
    const int i = blockIdx.x / K_CLS, j = blockIdx.x % K_CLS;
    int s = 0;
    for (int b = threadIdx.x; b < B_ROWS; b += 256)
        s += L[b * K_CLS + i] * L[b * K_CLS + j];
    for (int off = 32; off; off >>= 1) s += __shfl_down(s, off);
    __shared__ int red[4];
    if ((threadIdx.x & 63) == 0) red[threadIdx.x >> 6] = s;
    __syncthreads();
    if (threadIdx.x == 0)
        bc[blockIdx.x] = (float)(red[0] + red[1] + red[2] + red[3]) / (float)B_ROWS;
}

__global__ void cooccur_loss(const float* __restrict__ C, const float* __restrict__ bc,
                             float* __restrict__ out) {
    const int t = threadIdx.x;
    float d2 = 0.f;
    if (t < K_CLS * K_CLS) {
        float s = 1.0f / (1.0f + expf(-C[t]));
        float d = s - bc[t];
        d2 = d * d;
    }
    for (int off = 32; off; off >>= 1) d2 += __shfl_down(d2, off);
    __shared__ float red[4];
    if ((t & 63) == 0) red[t >> 6] = d2;
    __syncthreads();
    if (t == 0) out[0] = (red[0] + red[1] + red[2] + red[3]) / (float)(K_CLS * K_CLS);
}

// ---------- bf16 GEMM-BT: Y[m,n] = sum_k X[m,k]*W[n,k] + bias[n] ----------
// m97 structure: 128x128 tile, BK=32, 4 waves (2x2), 4x4 mfma_16x16x32 per wave.
__global__ __launch_bounds__(256) void gemm_bt(
    const u16* __restrict__ Xbf,   // [32768][4096] (image rows then text rows)
    const u16* __restrict__ Wbf,   // [2][4096][4096] (Wv, Wt)
    const float* __restrict__ bv, const float* __restrict__ bt,
    u16* __restrict__ Ybf)         // [32768][4096]
{
    __shared__ __align__(16) u16 As[128 * 32];   // 8 KB
    __shared__ __align__(16) u16 Bs[128 * 32];   // 8 KB

    const int tid = threadIdx.x;
    const int wave = tid >> 6, lane = tid & 63;
    const int bn0 = blockIdx.x * 128;
    const int bm0 = blockIdx.y * 128;
    const int half = (bm0 >= B_ROWS) ? 1 : 0;
    const u16* Wsel = Wbf + (size_t)half * D_DIM * D_DIM;
    const float* bias = half ? bt : bv;

    // staging: lane covers row = group*16 + lane/4, col = (lane%4)*8 (8 bf16 = 16B)
    const int srA = lane >> 2;
    const int sc  = (lane & 3) * 8;
    const int g0 = wave * 2, g1 = wave * 2 + 1;   // 16-row groups, 0..7
    const u16* Ag = Xbf + (size_t)bm0 * D_DIM;
    const u16* Bg = Wsel + (size_t)bn0 * D_DIM;
    const u16* ga0 = Ag + (size_t)(g0 * 16 + srA) * D_DIM + sc;
    const u16* ga1 = Ag + (size_t)(g1 * 16 + srA) * D_DIM + sc;
    const u16* gb0 = Bg + (size_t)(g0 * 16 + srA) * D_DIM + sc;
    const u16* gb1 = Bg + (size_t)(g1 * 16 + srA) * D_DIM + sc;
    u16* la0 = &As[g0 * 512]; u16* la1 = &As[g1 * 512];
    u16* lb0 = &Bs[g0 * 512]; u16* lb1 = &Bs[g1 * 512];

    const int waveM = wave >> 1, waveN = wave & 1;
    const int mlane = lane & 15, quad = lane >> 4;
    const u16* Ar = &As[(waveM * 64 + mlane) * 32 + quad * 8];
    const u16* Br = &Bs[(waveN * 64 + mlane) * 32 + quad * 8];

    f32x4 acc[4][4] = {};

    for (int k0 = 0; k0 < D_DIM; k0 += 32) {
        __syncthreads();                 // prev tile's ds_reads done before overwrite
        g2lds16(ga0 + k0, la0);
        g2lds16(ga1 + k0, la1);
        g2lds16(gb0 + k0, lb0);
        g2lds16(gb1 + k0, lb1);
        __syncthreads();                 // vmcnt(0) drain: staged data visible
        bf16x8 a[4], b[4];
#pragma unroll
        for (int mi = 0; mi < 4; mi++) a[mi] = *(const bf16x8*)(Ar + mi * 16 * 32);
#pragma unroll
        for (int ni = 0; ni < 4; ni++) b[ni] = *(const bf16x8*)(Br + ni * 16 * 32);
#pragma unroll
        for (int mi = 0; mi < 4; mi++)
#pragma unroll
            for (int ni = 0; ni < 4; ni++)
                acc[mi][ni] = __builtin_amdgcn_mfma_f32_16x16x32_bf16(
                    a[mi], b[ni], acc[mi][ni], 0, 0, 0);
    }

    // epilogue: C/D layout col=lane&15, row=quad*4+reg
#pragma unroll
    for (int ni = 0; ni < 4; ni++) {
        const int col = bn0 + waveN * 64 + ni * 16 + mlane;
        const float bcol = bias[col];
#pragma unroll
        for (int mi = 0; mi < 4; mi++) {
            f32x4 v = acc[mi][ni];
#pragma unroll
            for (int r = 0; r < 4; r++) {
                const int row = bm0 + waveM * 64 + mi * 16 + quad * 4 + r;
                Ybf[(size_t)row * D_DIM + col] = (u16)f2bf(v[r] + bcol);
            }
        }
    }
}

// ---------- sim + norm: sim[r][k] = (y_r . p_hat_k) / max(||y_r||, eps) ----------
// one wave handles 4 rows; lanes sweep D; shuffle-reduce 60 accumulators
__global__ __launch_bounds__(256) void simproj(
    const u16* __restrict__ Ybf, const u16* __restrict__ pTbf,
    float* __restrict__ sim)
{
    const int tid = threadIdx.x;
    const int wave = tid >> 6, lane = tid & 63;
    const int r0 = blockIdx.x * 16 + wave * 4;
    const u16* Y0 = Ybf + (size_t)r0 * D_DIM;

    float acc[4][15];
#pragma unroll
    for (int r = 0; r < 4; r++)
#pragma unroll
        for (int k = 0; k < 15; k++) acc[r][k] = 0.f;

#pragma unroll 2
    for (int i = 0; i < 64; i++) {
        const int d = lane + i * 64;
        const uint4* pq = (const uint4*)(pTbf + (size_t)d * 16);
        const uint4 q0 = pq[0], q1 = pq[1];
        const float p[14] = { bfl(q0.x), bfh(q0.x), bfl(q0.y), bfh(q0.y),
                              bfl(q0.z), bfh(q0.z), bfl(q0.w), bfh(q0.w),
                              bfl(q1.x), bfh(q1.x), bfl(q1.y), bfh(q1.y),
                              bfl(q1.z), bfh(q1.z) };
#pragma unroll
        for (int r = 0; r < 4; r++) {
            const float yv = bfl((u32)Y0[(size_t)r * D_DIM + d]);
            acc[r][14] += yv * yv;
#pragma unroll
            for (int k = 0; k < 14; k++) acc[r][k] += yv * p[k];
        }
    }
#pragma unroll
    for (int r = 0; r < 4; r++)
#pragma unroll
        for (int k = 0; k < 15; k++) {
            float v = acc[r][k];
            v += __shfl_xor(v, 1);  v += __shfl_xor(v, 2);  v += __shfl_xor(v, 4);
            v += __shfl_xor(v, 8);  v += __shfl_xor(v, 16); v += __shfl_xor(v, 32);
            acc[r][k] = v;
        }
    if (lane == 0) {
#pragma unroll
        for (int r = 0; r < 4; r++) {
            const float inv = 1.0f / fmaxf(sqrtf(acc[r][14]), 1e-12f);
#pragma unroll
            for (int k = 0; k < 14; k++)
                sim[(size_t)(r0 + r) * K_CLS + k] = acc[r][k] * inv;
        }
    }
}

// ---------- final: shapley = 0.5*(v_sim + t_sim)*label ----------
__global__ void finalize(const float* __restrict__ sim, const int* __restrict__ L,
                         float* __restrict__ out) {
    const int t = blockIdx.x * 256 + threadIdx.x;
    if (t >= B_ROWS * K_CLS) return;
    out[t] = 0.5f * (sim[t] + sim[t + B_ROWS * K_CLS]) * (float)L[t];
}

// ---------- launch ----------
extern "C" void kernel_launch(void* const* d_in, const int* in_sizes, int n_in,
                              void* d_out, int out_size, void* d_ws, size_t ws_size,
                              hipStream_t stream) {
    const float* image  = (const float*)d_in[0];
    const float* text   = (const float*)d_in[1];
    const int*   labels = (const int*)d_in[2];
    const float* Wv     = (const float*)d_in[3];
    const float* bv     = (const float*)d_in[4];
    const float* Wt     = (const float*)d_in[5];
    const float* bt     = (const float*)d_in[6];
    const float* protos = (const float*)d_in[7];
    const float* cooc   = (const float*)d_in[8];
    float* out = (float*)d_out;

    // workspace layout (bytes)
    const size_t OFF_X   = 0;                       // 268,435,456  x bf16 [32768][4096]
    const size_t OFF_W   = 268435456ull;            //  67,108,864  Wv,Wt bf16
    const size_t OFF_Y   = 335544320ull;            // 268,435,456  y bf16 [32768][4096]
    const size_t OFF_PT  = 603979776ull;            //     131,072  p_hat bf16 [4096][16]
    const size_t OFF_SIM = 604110848ull;            //   1,835,008  sim f32 [32768][14]
    const size_t OFF_BC  = 605945856ull;            //         784  bc f32 [196]
    const size_t NEED    = 605946640ull;
    if (ws_size < NEED) return;                     // loud failure if ws too small

    char* ws = (char*)d_ws;
    u16*   Xbf  = (u16*)(ws + OFF_X);
    u16*   Wbf  = (u16*)(ws + OFF_W);
    u16*   Ybf  = (u16*)(ws + OFF_Y);
    u16*   pTbf = (u16*)(ws + OFF_PT);
    float* sim  = (float*)(ws + OFF_SIM);
    float* bc   = (float*)(ws + OFF_BC);

    // casts
    cast_bf16<<<4096, 256, 0, stream>>>(image, Xbf, (B_ROWS * D_DIM) / 4);
    cast_bf16<<<4096, 256, 0, stream>>>(text, Xbf + (size_t)B_ROWS * D_DIM, (B_ROWS * D_DIM) / 4);
    cast_bf16<<<2048, 256, 0, stream>>>(Wv, Wbf, (D_DIM * D_DIM) / 4);
    cast_bf16<<<2048, 256, 0, stream>>>(Wt, Wbf + (size_t)D_DIM * D_DIM, (D_DIM * D_DIM) / 4);

    // small side computations
    proto_norm<<<K_CLS, 256, 0, stream>>>(protos, pTbf, out + B_ROWS * K_CLS);
    cooccur_bc<<<K_CLS * K_CLS, 256, 0, stream>>>(labels, bc);
    cooccur_loss<<<1, 256, 0, stream>>>(cooc, bc, out + B_ROWS * K_CLS + K_CLS * D_DIM);

    // main GEMM: grid (N/128, M/128); row-block picks Wv/Wt + bias
    gemm_bt<<<dim3(D_DIM / 128, M_TOT / 128), 256, 0, stream>>>(Xbf, Wbf, bv, bt, Ybf);

    // projection + normalization
    simproj<<<M_TOT / 16, 256, 0, stream>>>(Ybf, pTbf, sim);

    // combine halves with labels
    finalize<<<(B_ROWS * K_CLS + 255) / 256, 256, 0, stream>>>(sim, labels, out);
}